// Round 7
// baseline (510.468 us; speedup 1.0000x reference)
//
#include <hip/hip_runtime.h>
#include <hip/hip_bf16.h>

// Problem constants
#define NN 8192
#define DD 128
#define CC 1000
#define LN2 0.69314718f
#define G_SCALE 14.42695041f   // 10/ln2 : MFMA emits log2-domain scores
#define NSTRIP 32
#define JPER   256             // 8192/32 j-columns per strip
#define NTILE  4               // JPER/64
#define LROW   132             // u16 per LDS B-row: 264 B (stride 66 dw == 2 mod 32)
#define GRID_NCE 2048          // NSTRIP * 64
#define GRID_JSD 2048          // NN/4
#define GRID_TOT 4096

typedef short v8s __attribute__((ext_vector_type(8)));
typedef float v4f __attribute__((ext_vector_type(4)));
typedef unsigned short u16;
typedef unsigned int u32;

#if __has_builtin(__builtin_amdgcn_exp2f)
#define EXP2(x) __builtin_amdgcn_exp2f(x)
#else
#define EXP2(x) exp2f(x)
#endif
#if __has_builtin(__builtin_amdgcn_logf)
#define LOG2(x) __builtin_amdgcn_logf(x)
#else
#define LOG2(x) log2f(x)
#endif

// ---- helpers -------------------------------------------------------------
static __device__ __forceinline__ float bf2f(u16 u) {
    union { float f; u32 i; } x; x.i = ((u32)u) << 16; return x.f;
}
static __device__ __forceinline__ u16 f2bf(float f) {
    u32 x = __float_as_uint(f);
    return (u16)((x + 0x7FFFu + ((x >> 16) & 1u)) >> 16);  // RNE
}
static __device__ __forceinline__ float wsum(float v) {
    #pragma unroll
    for (int m = 1; m < 64; m <<= 1) v += __shfl_xor(v, m, 64);
    return v;
}
static __device__ __forceinline__ float wmax(float v) {
    #pragma unroll
    for (int m = 1; m < 64; m <<= 1) v = fmaxf(v, __shfl_xor(v, m, 64));
    return v;
}

// ---- prep: barrier-free, one WAVE per feature row ------------------------
// Lane loads one u32 = detect word AND (if bf16) the data pair; 64 lanes x 2
// elems = 128 cols. Full-wave shuffle reduce; paired-bf16 u32 store.
// Blocks [0,4096): 4 rows each. Blocks [4096,4128): decode 256 targets each.
__global__ __launch_bounds__(256) void prep_kernel(const void* __restrict__ fs,
                                                   const void* __restrict__ ft,
                                                   const int* __restrict__ traw,
                                                   u16* __restrict__ f1, u16* __restrict__ f2,
                                                   int* __restrict__ tgt32,
                                                   int* __restrict__ counts) {
    int b = blockIdx.x, tid = threadIdx.x;
    int w = tid >> 6, lane = tid & 63;
    if (b < 4096) {
        int row4 = b * 4 + w;                 // 0..16383
        const void* src; u16* dst; float gain; int row;
        if (row4 < NN) { src = fs; dst = f1; gain = G_SCALE; row = row4; }
        else           { src = ft; dst = f2; gain = 1.0f;    row = row4 - NN; }
        u32 wb = ((const u32*)src)[(size_t)row * 64 + lane];
        unsigned e = (wb >> 7) & 0xFF;
        int isF32 = (__popcll(__ballot(e >= 100 && e <= 140)) < 32);
        float x0, x1;
        if (isF32) {
            float2 v = ((const float2*)src)[(size_t)row * 64 + lane];
            x0 = v.x; x1 = v.y;
        } else {
            x0 = bf2f((u16)(wb & 0xFFFF));
            x1 = bf2f((u16)(wb >> 16));
        }
        float ss = wsum(x0 * x0 + x1 * x1);
        float sc = gain / fmaxf(sqrtf(ss), 1e-12f);
        u32 outw = (u32)f2bf(x0 * sc) | ((u32)f2bf(x1 * sc) << 16);
        ((u32*)dst)[(size_t)row * 64 + lane] = outw;
    } else {
        int db = b - 4096;                    // 0..31
        int idx = db * 256 + tid;             // target index 0..8191
        // int64-vs-int32 detect on odd dwords, in-bounds under both widths
        int k = db * 128 + (tid & 127);       // < 4096
        int odd = traw[2 * k + 1];
        int is32 = (__ballot(odd != 0) != 0ull);
        int t = (is32 ? traw[idx] : traw[2 * idx]) & 127;
        tgt32[idx] = t;
        atomicAdd(&counts[t], 1);
    }
}

// ---- fused NCE (blocks < 2048) + JSD (blocks >= 2048) + finale -----------
// NCE: 128 i-rows x 256 j-strip. B double-buffered in padded LDS, ONE
// barrier per tile (WAR across two iterations is protected by that barrier).
// Per row accumulate P = sum_j 2^s2, Q = sum_pos 2^s2, S = sum_pos s2 into
// per-row global atomics. Every block ends with release fence + done count;
// the last block reduces the 8192 row losses and writes the output.
__global__ __launch_bounds__(256) void main_kernel(const u16* __restrict__ f1,
                                                   const u16* __restrict__ f2,
                                                   const int* __restrict__ tgt,
                                                   const void* __restrict__ ls,
                                                   const void* __restrict__ lt,
                                                   const int* __restrict__ counts,
                                                   float* __restrict__ Pp,
                                                   float* __restrict__ Qp,
                                                   float* __restrict__ Sp,
                                                   float* __restrict__ sums,
                                                   u32* __restrict__ out) {
    __shared__ u16 lds[2][64 * LROW];   // 33792 B
    __shared__ float sred[4];
    __shared__ int lastf;
    int bx = blockIdx.x;
    int tid = threadIdx.x;
    int w = tid >> 6, lane = tid & 63;

    if (bx < GRID_NCE) {
        // ------------------- NCE path -------------------
        int strip = bx & 31;
        int ib = bx >> 5;
        int quad = lane >> 4, lcol = lane & 15;
        int ibase = ib * 128 + w * 32;

        v8s a0[4], a1[4];
        #pragma unroll
        for (int t = 0; t < 4; t++) {
            int k = t * 32 + quad * 8;
            a0[t] = *(const v8s*)(f1 + (size_t)(ibase + lcol) * DD + k);
            a1[t] = *(const v8s*)(f1 + (size_t)(ibase + 16 + lcol) * DD + k);
        }
        int ti[8];
        #pragma unroll
        for (int a = 0; a < 2; a++)
            #pragma unroll
            for (int v = 0; v < 4; v++)
                ti[a * 4 + v] = tgt[ibase + a * 16 + quad * 4 + v];

        float P[8] = {}, Q[8] = {}, S[8] = {};

        int srow = tid >> 4;           // 0..15
        int schunk = tid & 15;         // 0..15
        const u16* gb = f2 + (size_t)strip * JPER * DD;

        float4 st[4];
        #pragma unroll
        for (int r = 0; r < 4; r++)
            st[r] = *(const float4*)(gb + (size_t)(r * 16 + srow) * DD + schunk * 8);

        for (int it = 0; it < NTILE; ++it) {
            u16* buf = lds[it & 1];
            #pragma unroll
            for (int r = 0; r < 4; r++)
                *(float4*)(buf + (r * 16 + srow) * LROW + schunk * 8) = st[r];
            __syncthreads();
            if (it + 1 < NTILE) {     // prefetch next tile; hidden by compute
                const u16* g2 = gb + (size_t)(it + 1) * 64 * DD;
                #pragma unroll
                for (int r = 0; r < 4; r++)
                    st[r] = *(const float4*)(g2 + (size_t)(r * 16 + srow) * DD + schunk * 8);
            }
            int jb = strip * JPER + it * 64;
            int tj0 = tgt[jb + lcol];
            int tj1 = tgt[jb + 16 + lcol];
            int tj2 = tgt[jb + 32 + lcol];
            int tj3 = tgt[jb + 48 + lcol];

            const u16* lb = buf + lcol * LROW + quad * 8;
            v4f zero = {0.f, 0.f, 0.f, 0.f};
            v4f acc[8] = {zero, zero, zero, zero, zero, zero, zero, zero};
            #pragma unroll
            for (int t = 0; t < 4; t++) {
                v8s b0 = *(const v8s*)(lb + 0 * 16 * LROW + t * 32);
                v8s b1 = *(const v8s*)(lb + 1 * 16 * LROW + t * 32);
                v8s b2 = *(const v8s*)(lb + 2 * 16 * LROW + t * 32);
                v8s b3 = *(const v8s*)(lb + 3 * 16 * LROW + t * 32);
                acc[0] = __builtin_amdgcn_mfma_f32_16x16x32_bf16(a0[t], b0, acc[0], 0, 0, 0);
                acc[1] = __builtin_amdgcn_mfma_f32_16x16x32_bf16(a0[t], b1, acc[1], 0, 0, 0);
                acc[2] = __builtin_amdgcn_mfma_f32_16x16x32_bf16(a0[t], b2, acc[2], 0, 0, 0);
                acc[3] = __builtin_amdgcn_mfma_f32_16x16x32_bf16(a0[t], b3, acc[3], 0, 0, 0);
                acc[4] = __builtin_amdgcn_mfma_f32_16x16x32_bf16(a1[t], b0, acc[4], 0, 0, 0);
                acc[5] = __builtin_amdgcn_mfma_f32_16x16x32_bf16(a1[t], b1, acc[5], 0, 0, 0);
                acc[6] = __builtin_amdgcn_mfma_f32_16x16x32_bf16(a1[t], b2, acc[6], 0, 0, 0);
                acc[7] = __builtin_amdgcn_mfma_f32_16x16x32_bf16(a1[t], b3, acc[7], 0, 0, 0);
            }
            #pragma unroll
            for (int a = 0; a < 2; a++) {
                #pragma unroll
                for (int v = 0; v < 4; v++) {
                    int t_i = ti[a * 4 + v];
                    #pragma unroll
                    for (int jf = 0; jf < 4; jf++) {
                        float s2 = acc[a * 4 + jf][v];
                        float e1 = EXP2(s2);
                        int tj = (jf == 0) ? tj0 : (jf == 1) ? tj1 : (jf == 2) ? tj2 : tj3;
                        bool pos = (tj == t_i);
                        P[a * 4 + v] += e1;
                        Q[a * 4 + v] += pos ? e1 : 0.0f;
                        S[a * 4 + v] += pos ? s2 : 0.0f;
                    }
                }
            }
        }

        #pragma unroll
        for (int a = 0; a < 2; a++) {
            #pragma unroll
            for (int v = 0; v < 4; v++) {
                float p = P[a * 4 + v], q = Q[a * 4 + v], s = S[a * 4 + v];
                #pragma unroll
                for (int m = 1; m < 16; m <<= 1) {
                    p += __shfl_xor(p, m, 64);
                    q += __shfl_xor(q, m, 64);
                    s += __shfl_xor(s, m, 64);
                }
                if (lcol == 0) {
                    int row = ibase + a * 16 + quad * 4 + v;
                    atomicAdd(&Pp[row], p);
                    atomicAdd(&Qp[row], q);
                    atomicAdd(&Sp[row], s);
                }
            }
        }
    } else {
        // ------------------- JSD path (wave per row) -------------------
        int row = (bx - GRID_NCE) * 4 + w;
        u32 wb = ((const u32*)ls)[(size_t)row * 500 + lane];
        unsigned e = (wb >> 7) & 0xFF;
        int isF32 = (__popcll(__ballot(e >= 100 && e <= 140)) < 32);

        float xs[16], xt[16];
        #pragma unroll
        for (int c = 0; c < 4; c++) {
            int idx = c * 256 + lane * 4;
            if (idx < CC) {
                if (isF32) {
                    float4 a = *(const float4*)((const float*)ls + (size_t)row * CC + idx);
                    float4 b = *(const float4*)((const float*)lt + (size_t)row * CC + idx);
                    xs[c*4+0] = a.x; xs[c*4+1] = a.y; xs[c*4+2] = a.z; xs[c*4+3] = a.w;
                    xt[c*4+0] = b.x; xt[c*4+1] = b.y; xt[c*4+2] = b.z; xt[c*4+3] = b.w;
                } else {
                    ushort4 a = *(const ushort4*)((const u16*)ls + (size_t)row * CC + idx);
                    ushort4 b = *(const ushort4*)((const u16*)lt + (size_t)row * CC + idx);
                    xs[c*4+0] = bf2f(a.x); xs[c*4+1] = bf2f(a.y); xs[c*4+2] = bf2f(a.z); xs[c*4+3] = bf2f(a.w);
                    xt[c*4+0] = bf2f(b.x); xt[c*4+1] = bf2f(b.y); xt[c*4+2] = bf2f(b.z); xt[c*4+3] = bf2f(b.w);
                }
            } else {
                #pragma unroll
                for (int q = 0; q < 4; q++) { xs[c*4+q] = -1e30f; xt[c*4+q] = -1e30f; }
            }
        }
        float ms = -1e30f, mt = -1e30f;
        #pragma unroll
        for (int q = 0; q < 16; q++) { ms = fmaxf(ms, xs[q]); mt = fmaxf(mt, xt[q]); }
        ms = wmax(ms); mt = wmax(mt);
        float es = 0.f, et = 0.f;
        #pragma unroll
        for (int q = 0; q < 16; q++) { es += __expf(xs[q] - ms); et += __expf(xt[q] - mt); }
        es = wsum(es); et = wsum(et);
        float lse_s = ms + __logf(es), lse_t = mt + __logf(et);
        float contrib = 0.f;
        #pragma unroll
        for (int q = 0; q < 16; q++) {
            float lps = xs[q] - lse_s, lpt = xt[q] - lse_t;
            contrib += (lpt - lps) * (__expf(lpt) - __expf(lps));
        }
        contrib = wsum(contrib);
        if (lane == 0) sred[w] = contrib;
        __syncthreads();
        if (tid == 0) atomicAdd(&sums[1], sred[0] + sred[1] + sred[2] + sred[3]);
    }

    // ---------------- shared tail: done-count + finale ----------------
    __threadfence();            // release: this wave's atomics visible device-wide
    __syncthreads();            // all waves of this block fenced
    if (tid == 0) {
        int* done = (int*)sums + 2;
        lastf = (atomicAdd(done, 1) == GRID_TOT - 1);
    }
    __syncthreads();
    if (!lastf) return;
    __threadfence();            // acquire side

    float lsum = 0.f;
    #pragma unroll 4
    for (int k2 = 0; k2 < 32; k2++) {
        int i = tid + 256 * k2;
        float P = __hip_atomic_load(&Pp[i], __ATOMIC_RELAXED, __HIP_MEMORY_SCOPE_AGENT);
        float Q = __hip_atomic_load(&Qp[i], __ATOMIC_RELAXED, __HIP_MEMORY_SCOPE_AGENT);
        float S = __hip_atomic_load(&Sp[i], __ATOMIC_RELAXED, __HIP_MEMORY_SCOPE_AGENT);
        int cnt = counts[tgt[i]];
        float pos = LN2 * LOG2(P) - LN2 * S / (float)cnt;
        float neg = (1.0f - Q / P) / (float)(NN - cnt);
        lsum += pos + neg;
    }
    lsum = wsum(lsum);
    if (lane == 0) sred[w] = lsum;
    __syncthreads();
    if (tid == 0) {
        float Jsum = __hip_atomic_load(&sums[1], __ATOMIC_RELAXED, __HIP_MEMORY_SCOPE_AGENT);
        float loss = (sred[0] + sred[1] + sred[2] + sred[3] + 0.5f * Jsum) / (float)NN;
        u32 fb = __float_as_uint(loss);
        out[0] = (fb & 0xFFFF0000u) | (u32)f2bf(loss);
    }
}

// ---- launch --------------------------------------------------------------
extern "C" void kernel_launch(void* const* d_in, const int* in_sizes, int n_in,
                              void* d_out, int out_size, void* d_ws, size_t ws_size,
                              hipStream_t stream) {
    const void* fs = d_in[0];
    const void* ft = d_in[1];
    const void* ls = d_in[2];
    const void* lt = d_in[3];
    const int* tgt_raw = (const int*)d_in[4];

    char* wsp = (char*)d_ws;
    u16*   f1     = (u16*)(wsp + 0);           // 2 MiB
    u16*   f2     = (u16*)(wsp + 2097152);     // 2 MiB
    float* Pp     = (float*)(wsp + 4194304);   // 32 KiB  -- zeroed
    float* Qp     = (float*)(wsp + 4227072);   // 32 KiB  -- zeroed
    float* Sp     = (float*)(wsp + 4259840);   // 32 KiB  -- zeroed
    int*   counts = (int*)(wsp + 4292608);     // 512 B   -- zeroed
    float* sums   = (float*)(wsp + 4293120);   // 16 B    -- zeroed (spare,Jsum,done)
    int*   tgt32  = (int*)(wsp + 4293376);     // 32 KiB

    hipMemsetAsync(wsp + 4194304, 0, 98832, stream);  // Pp..sums contiguous
    prep_kernel<<<4096 + 32, 256, 0, stream>>>(fs, ft, tgt_raw, f1, f2, tgt32, counts);
    main_kernel<<<GRID_TOT, 256, 0, stream>>>(f1, f2, tgt32, ls, lt, counts,
                                              Pp, Qp, Sp, sums, (u32*)d_out);
}

// Round 8
// 252.240 us; speedup vs baseline: 2.0237x; 2.0237x over previous
//
#include <hip/hip_runtime.h>
#include <hip/hip_bf16.h>

// Problem constants
#define NN 8192
#define DD 128
#define CC 1000
#define LN2 0.69314718f
#define G_SCALE 14.42695041f   // 10/ln2 : MFMA emits log2-domain scores
#define NSTRIP 32
#define JPER   256             // 8192/32 j-columns per strip
#define NTILE  4               // JPER/64
#define LROW   132             // u16 per LDS B-row: 264 B (66 dw == 2 mod 32 -> conflict-free)
#define GRID_NCE 2048          // NSTRIP * 64
#define GRID_TOT 4096          // + NN/4 JSD blocks

typedef short v8s __attribute__((ext_vector_type(8)));
typedef float v4f __attribute__((ext_vector_type(4)));
typedef unsigned short u16;
typedef unsigned int u32;

#if __has_builtin(__builtin_amdgcn_exp2f)
#define EXP2(x) __builtin_amdgcn_exp2f(x)
#else
#define EXP2(x) exp2f(x)
#endif
#if __has_builtin(__builtin_amdgcn_logf)
#define LOG2(x) __builtin_amdgcn_logf(x)
#else
#define LOG2(x) log2f(x)
#endif

// ---- helpers -------------------------------------------------------------
static __device__ __forceinline__ float bf2f(u16 u) {
    union { float f; u32 i; } x; x.i = ((u32)u) << 16; return x.f;
}
static __device__ __forceinline__ u16 f2bf(float f) {
    u32 x = __float_as_uint(f);
    return (u16)((x + 0x7FFFu + ((x >> 16) & 1u)) >> 16);  // RNE
}
static __device__ __forceinline__ float wsum(float v) {
    #pragma unroll
    for (int m = 1; m < 64; m <<= 1) v += __shfl_xor(v, m, 64);
    return v;
}
static __device__ __forceinline__ float wmax(float v) {
    #pragma unroll
    for (int m = 1; m < 64; m <<= 1) v = fmaxf(v, __shfl_xor(v, m, 64));
    return v;
}

// ---- prep: barrier-free, one WAVE per feature row (4 rows per wave) ------
// Lane loads one u32 = dtype-detect word AND (if bf16) the data pair; 64
// lanes x 2 elems = 128 cols. Full-wave shuffle reduce; paired-bf16 store.
// Blocks [0,1024): 16 rows each. Blocks [1024,1032): decode 1024 targets.
__global__ __launch_bounds__(256) void prep_kernel(const void* __restrict__ fs,
                                                   const void* __restrict__ ft,
                                                   const int* __restrict__ traw,
                                                   u16* __restrict__ f1, u16* __restrict__ f2,
                                                   int* __restrict__ tgt32,
                                                   int* __restrict__ counts) {
    int b = blockIdx.x, tid = threadIdx.x;
    int w = tid >> 6, lane = tid & 63;
    if (b < 1024) {
        #pragma unroll
        for (int r = 0; r < 4; r++) {
            int row4 = b * 16 + w * 4 + r;        // 0..16383
            const void* src; u16* dst; float gain; int row;
            if (row4 < NN) { src = fs; dst = f1; gain = G_SCALE; row = row4; }
            else           { src = ft; dst = f2; gain = 1.0f;    row = row4 - NN; }
            u32 wb = ((const u32*)src)[(size_t)row * 64 + lane];
            unsigned e = (wb >> 7) & 0xFF;
            int isF32 = (__popcll(__ballot(e >= 100 && e <= 140)) < 32);
            float x0, x1;
            if (isF32) {
                float2 v = ((const float2*)src)[(size_t)row * 64 + lane];
                x0 = v.x; x1 = v.y;
            } else {
                x0 = bf2f((u16)(wb & 0xFFFF));
                x1 = bf2f((u16)(wb >> 16));
            }
            float ss = wsum(x0 * x0 + x1 * x1);
            float sc = gain / fmaxf(sqrtf(ss), 1e-12f);
            u32 outw = (u32)f2bf(x0 * sc) | ((u32)f2bf(x1 * sc) << 16);
            ((u32*)dst)[(size_t)row * 64 + lane] = outw;
        }
    } else {
        int db = b - 1024;                    // 0..7
        #pragma unroll
        for (int r = 0; r < 4; r++) {
            int idx = db * 1024 + r * 256 + tid;   // target index 0..8191
            // int64-vs-int32 detect on odd dwords, in-bounds under both widths
            int k = (idx >> 1) & 4095;
            int odd = traw[2 * k + 1];
            int is32 = (__ballot(odd != 0) != 0ull);
            int t = (is32 ? traw[idx] : traw[2 * idx]) & 127;
            tgt32[idx] = t;
            atomicAdd(&counts[t], 1);
        }
    }
}

// ---- fused NCE (blocks < 2048) + JSD (blocks >= 2048) --------------------
// NCE: 128 i-rows x 256 j-strip. B double-buffered in padded LDS, ONE
// barrier per tile (the barrier of iteration `it` also protects the WAR on
// buffer it&1 two iterations later). Per row accumulate P = sum_j 2^s2,
// Q = sum_pos 2^s2, S = sum_pos s2 into per-row global atomics. NO fences.
__global__ __launch_bounds__(256) void main_kernel(const u16* __restrict__ f1,
                                                   const u16* __restrict__ f2,
                                                   const int* __restrict__ tgt,
                                                   const void* __restrict__ ls,
                                                   const void* __restrict__ lt,
                                                   float* __restrict__ Pp,
                                                   float* __restrict__ Qp,
                                                   float* __restrict__ Sp,
                                                   float* __restrict__ sums) {
    __shared__ u16 lds[2][64 * LROW];   // 33792 B
    __shared__ float sred[4];
    int bx = blockIdx.x;
    int tid = threadIdx.x;
    int w = tid >> 6, lane = tid & 63;

    if (bx < GRID_NCE) {
        // ------------------- NCE path -------------------
        int strip = bx & 31;
        int ib = bx >> 5;
        int quad = lane >> 4, lcol = lane & 15;
        int ibase = ib * 128 + w * 32;

        v8s a0[4], a1[4];
        #pragma unroll
        for (int t = 0; t < 4; t++) {
            int k = t * 32 + quad * 8;
            a0[t] = *(const v8s*)(f1 + (size_t)(ibase + lcol) * DD + k);
            a1[t] = *(const v8s*)(f1 + (size_t)(ibase + 16 + lcol) * DD + k);
        }
        int ti[8];
        #pragma unroll
        for (int a = 0; a < 2; a++)
            #pragma unroll
            for (int v = 0; v < 4; v++)
                ti[a * 4 + v] = tgt[ibase + a * 16 + quad * 4 + v];

        float P[8] = {}, Q[8] = {}, S[8] = {};

        int srow = tid >> 4;           // 0..15
        int schunk = tid & 15;         // 0..15
        const u16* gb = f2 + (size_t)strip * JPER * DD;

        float4 st[4];
        #pragma unroll
        for (int r = 0; r < 4; r++)
            st[r] = *(const float4*)(gb + (size_t)(r * 16 + srow) * DD + schunk * 8);

        for (int it = 0; it < NTILE; ++it) {
            u16* buf = lds[it & 1];
            #pragma unroll
            for (int r = 0; r < 4; r++)
                *(float4*)(buf + (r * 16 + srow) * LROW + schunk * 8) = st[r];
            __syncthreads();
            if (it + 1 < NTILE) {     // prefetch next tile; hidden by compute
                const u16* g2 = gb + (size_t)(it + 1) * 64 * DD;
                #pragma unroll
                for (int r = 0; r < 4; r++)
                    st[r] = *(const float4*)(g2 + (size_t)(r * 16 + srow) * DD + schunk * 8);
            }
            int jb = strip * JPER + it * 64;
            int tj0 = tgt[jb + lcol];
            int tj1 = tgt[jb + 16 + lcol];
            int tj2 = tgt[jb + 32 + lcol];
            int tj3 = tgt[jb + 48 + lcol];

            const u16* lb = buf + lcol * LROW + quad * 8;
            v4f zero = {0.f, 0.f, 0.f, 0.f};
            v4f acc[8] = {zero, zero, zero, zero, zero, zero, zero, zero};
            #pragma unroll
            for (int t = 0; t < 4; t++) {
                v8s b0 = *(const v8s*)(lb + 0 * 16 * LROW + t * 32);
                v8s b1 = *(const v8s*)(lb + 1 * 16 * LROW + t * 32);
                v8s b2 = *(const v8s*)(lb + 2 * 16 * LROW + t * 32);
                v8s b3 = *(const v8s*)(lb + 3 * 16 * LROW + t * 32);
                acc[0] = __builtin_amdgcn_mfma_f32_16x16x32_bf16(a0[t], b0, acc[0], 0, 0, 0);
                acc[1] = __builtin_amdgcn_mfma_f32_16x16x32_bf16(a0[t], b1, acc[1], 0, 0, 0);
                acc[2] = __builtin_amdgcn_mfma_f32_16x16x32_bf16(a0[t], b2, acc[2], 0, 0, 0);
                acc[3] = __builtin_amdgcn_mfma_f32_16x16x32_bf16(a0[t], b3, acc[3], 0, 0, 0);
                acc[4] = __builtin_amdgcn_mfma_f32_16x16x32_bf16(a1[t], b0, acc[4], 0, 0, 0);
                acc[5] = __builtin_amdgcn_mfma_f32_16x16x32_bf16(a1[t], b1, acc[5], 0, 0, 0);
                acc[6] = __builtin_amdgcn_mfma_f32_16x16x32_bf16(a1[t], b2, acc[6], 0, 0, 0);
                acc[7] = __builtin_amdgcn_mfma_f32_16x16x32_bf16(a1[t], b3, acc[7], 0, 0, 0);
            }
            #pragma unroll
            for (int a = 0; a < 2; a++) {
                #pragma unroll
                for (int v = 0; v < 4; v++) {
                    int t_i = ti[a * 4 + v];
                    #pragma unroll
                    for (int jf = 0; jf < 4; jf++) {
                        float s2 = acc[a * 4 + jf][v];
                        float e1 = EXP2(s2);
                        int tj = (jf == 0) ? tj0 : (jf == 1) ? tj1 : (jf == 2) ? tj2 : tj3;
                        bool pos = (tj == t_i);
                        P[a * 4 + v] += e1;
                        Q[a * 4 + v] += pos ? e1 : 0.0f;
                        S[a * 4 + v] += pos ? s2 : 0.0f;
                    }
                }
            }
        }

        #pragma unroll
        for (int a = 0; a < 2; a++) {
            #pragma unroll
            for (int v = 0; v < 4; v++) {
                float p = P[a * 4 + v], q = Q[a * 4 + v], s = S[a * 4 + v];
                #pragma unroll
                for (int m = 1; m < 16; m <<= 1) {
                    p += __shfl_xor(p, m, 64);
                    q += __shfl_xor(q, m, 64);
                    s += __shfl_xor(s, m, 64);
                }
                if (lcol == 0) {
                    int row = ibase + a * 16 + quad * 4 + v;
                    atomicAdd(&Pp[row], p);
                    atomicAdd(&Qp[row], q);
                    atomicAdd(&Sp[row], s);
                }
            }
        }
    } else {
        // ------------------- JSD path (wave per row) -------------------
        int row = (bx - GRID_NCE) * 4 + w;
        u32 wb = ((const u32*)ls)[(size_t)row * 500 + lane];
        unsigned e = (wb >> 7) & 0xFF;
        int isF32 = (__popcll(__ballot(e >= 100 && e <= 140)) < 32);

        float xs[16], xt[16];
        #pragma unroll
        for (int c = 0; c < 4; c++) {
            int idx = c * 256 + lane * 4;
            if (idx < CC) {
                if (isF32) {
                    float4 a = *(const float4*)((const float*)ls + (size_t)row * CC + idx);
                    float4 b = *(const float4*)((const float*)lt + (size_t)row * CC + idx);
                    xs[c*4+0] = a.x; xs[c*4+1] = a.y; xs[c*4+2] = a.z; xs[c*4+3] = a.w;
                    xt[c*4+0] = b.x; xt[c*4+1] = b.y; xt[c*4+2] = b.z; xt[c*4+3] = b.w;
                } else {
                    ushort4 a = *(const ushort4*)((const u16*)ls + (size_t)row * CC + idx);
                    ushort4 b = *(const ushort4*)((const u16*)lt + (size_t)row * CC + idx);
                    xs[c*4+0] = bf2f(a.x); xs[c*4+1] = bf2f(a.y); xs[c*4+2] = bf2f(a.z); xs[c*4+3] = bf2f(a.w);
                    xt[c*4+0] = bf2f(b.x); xt[c*4+1] = bf2f(b.y); xt[c*4+2] = bf2f(b.z); xt[c*4+3] = bf2f(b.w);
                }
            } else {
                #pragma unroll
                for (int q = 0; q < 4; q++) { xs[c*4+q] = -1e30f; xt[c*4+q] = -1e30f; }
            }
        }
        float ms = -1e30f, mt = -1e30f;
        #pragma unroll
        for (int q = 0; q < 16; q++) { ms = fmaxf(ms, xs[q]); mt = fmaxf(mt, xt[q]); }
        ms = wmax(ms); mt = wmax(mt);
        float es = 0.f, et = 0.f;
        #pragma unroll
        for (int q = 0; q < 16; q++) { es += __expf(xs[q] - ms); et += __expf(xt[q] - mt); }
        es = wsum(es); et = wsum(et);
        float lse_s = ms + __logf(es), lse_t = mt + __logf(et);
        float contrib = 0.f;
        #pragma unroll
        for (int q = 0; q < 16; q++) {
            float lps = xs[q] - lse_s, lpt = xt[q] - lse_t;
            contrib += (lpt - lps) * (__expf(lpt) - __expf(lps));
        }
        contrib = wsum(contrib);
        if (lane == 0) sred[w] = contrib;
        __syncthreads();
        if (tid == 0) atomicAdd(&sums[1], sred[0] + sred[1] + sred[2] + sred[3]);
    }
}

// ---- rowred + finalize ---------------------------------------------------
// 32 blocks x 256, one row per thread. Cross-dispatch visibility of main's
// atomics is guaranteed at the kernel boundary (plain loads OK). Only these
// 32 blocks use the done-counter + fence (negligible at this scale).
__global__ __launch_bounds__(256) void rowred_kernel(const float* __restrict__ Pp,
                                                     const float* __restrict__ Qp,
                                                     const float* __restrict__ Sp,
                                                     const int* __restrict__ tgt,
                                                     const int* __restrict__ counts,
                                                     float* __restrict__ sums,
                                                     u32* __restrict__ out) {
    __shared__ float sb[4];
    __shared__ int lastf;
    int tid = threadIdx.x;
    int i = blockIdx.x * 256 + tid;
    float P = Pp[i], Q = Qp[i], S = Sp[i];
    int cnt = counts[tgt[i]];
    float pos = LN2 * LOG2(P) - LN2 * S / (float)cnt;
    float neg = (1.0f - Q / P) / (float)(NN - cnt);
    float l = wsum(pos + neg);
    if ((tid & 63) == 0) sb[tid >> 6] = l;
    __syncthreads();
    if (tid == 0) {
        atomicAdd(&sums[0], sb[0] + sb[1] + sb[2] + sb[3]);
        __threadfence();
        int* done = (int*)sums + 2;
        lastf = (atomicAdd(done, 1) == 31);
    }
    __syncthreads();
    if (!lastf) return;
    if (tid == 0) {
        float Lsum = __hip_atomic_load(&sums[0], __ATOMIC_RELAXED, __HIP_MEMORY_SCOPE_AGENT);
        float Jsum = __hip_atomic_load(&sums[1], __ATOMIC_RELAXED, __HIP_MEMORY_SCOPE_AGENT);
        float loss = (Lsum + 0.5f * Jsum) / (float)NN;
        u32 fb = __float_as_uint(loss);
        out[0] = (fb & 0xFFFF0000u) | (u32)f2bf(loss);   // dual bf16/fp32 word
    }
}

// ---- launch --------------------------------------------------------------
extern "C" void kernel_launch(void* const* d_in, const int* in_sizes, int n_in,
                              void* d_out, int out_size, void* d_ws, size_t ws_size,
                              hipStream_t stream) {
    const void* fs = d_in[0];
    const void* ft = d_in[1];
    const void* ls = d_in[2];
    const void* lt = d_in[3];
    const int* tgt_raw = (const int*)d_in[4];

    char* wsp = (char*)d_ws;
    u16*   f1     = (u16*)(wsp + 0);           // 2 MiB
    u16*   f2     = (u16*)(wsp + 2097152);     // 2 MiB
    float* Pp     = (float*)(wsp + 4194304);   // 32 KiB  -- zeroed
    float* Qp     = (float*)(wsp + 4227072);   // 32 KiB  -- zeroed
    float* Sp     = (float*)(wsp + 4259840);   // 32 KiB  -- zeroed
    int*   counts = (int*)(wsp + 4292608);     // 512 B   -- zeroed
    float* sums   = (float*)(wsp + 4293120);   // 16 B    -- zeroed (Lsum,Jsum,done)
    int*   tgt32  = (int*)(wsp + 4293376);     // 32 KiB

    hipMemsetAsync(wsp + 4194304, 0, 98832, stream);  // Pp..sums contiguous
    prep_kernel<<<1024 + 8, 256, 0, stream>>>(fs, ft, tgt_raw, f1, f2, tgt32, counts);
    main_kernel<<<GRID_TOT, 256, 0, stream>>>(f1, f2, tgt32, ls, lt, Pp, Qp, Sp, sums);
    rowred_kernel<<<32, 256, 0, stream>>>(Pp, Qp, Sp, tgt32, counts, sums, (u32*)d_out);
}

// Round 9
// 222.370 us; speedup vs baseline: 2.2956x; 1.1343x over previous
//
#include <hip/hip_runtime.h>
#include <hip/hip_bf16.h>

// Problem constants
#define NN 8192
#define DD 128
#define CC 1000
#define LN2 0.69314718f
#define G_SCALE 14.42695041f   // 10/ln2 : MFMA emits log2-domain scores
#define NSTRIP 16
#define JPER   512             // 8192/16 j-columns per strip
#define NTILE  8               // JPER/64
#define LROW   132             // u16 per LDS B-row: 264 B (66 dw == 2 mod 32 -> conflict-free)
#define GRID_NCE 1024          // NSTRIP * 64
#define GRID_TOT 3072          // + NN/4 JSD blocks

typedef short v8s __attribute__((ext_vector_type(8)));
typedef float v4f __attribute__((ext_vector_type(4)));
typedef unsigned short u16;
typedef unsigned int u32;

#if __has_builtin(__builtin_amdgcn_exp2f)
#define EXP2(x) __builtin_amdgcn_exp2f(x)
#else
#define EXP2(x) exp2f(x)
#endif
#if __has_builtin(__builtin_amdgcn_logf)
#define LOG2(x) __builtin_amdgcn_logf(x)
#else
#define LOG2(x) log2f(x)
#endif

// ---- helpers -------------------------------------------------------------
static __device__ __forceinline__ float bf2f(u16 u) {
    union { float f; u32 i; } x; x.i = ((u32)u) << 16; return x.f;
}
static __device__ __forceinline__ u16 f2bf(float f) {
    u32 x = __float_as_uint(f);
    return (u16)((x + 0x7FFFu + ((x >> 16) & 1u)) >> 16);  // RNE
}
static __device__ __forceinline__ float wsum(float v) {
    #pragma unroll
    for (int m = 1; m < 64; m <<= 1) v += __shfl_xor(v, m, 64);
    return v;
}
static __device__ __forceinline__ float wmax(float v) {
    #pragma unroll
    for (int m = 1; m < 64; m <<= 1) v = fmaxf(v, __shfl_xor(v, m, 64));
    return v;
}

// ---- prep: barrier-free, one WAVE per feature row (4 rows per wave) ------
// Blocks [0,1024): 16 rows each. Blocks [1024,1032): decode 1024 targets
// each; block 1024 additionally zeroes the sums accumulators.
__global__ __launch_bounds__(256) void prep_kernel(const void* __restrict__ fs,
                                                   const void* __restrict__ ft,
                                                   const int* __restrict__ traw,
                                                   u16* __restrict__ f1, u16* __restrict__ f2,
                                                   int* __restrict__ tgt32,
                                                   float* __restrict__ sums) {
    int b = blockIdx.x, tid = threadIdx.x;
    int w = tid >> 6, lane = tid & 63;
    if (b < 1024) {
        #pragma unroll
        for (int r = 0; r < 4; r++) {
            int row4 = b * 16 + w * 4 + r;        // 0..16383
            const void* src; u16* dst; float gain; int row;
            if (row4 < NN) { src = fs; dst = f1; gain = G_SCALE; row = row4; }
            else           { src = ft; dst = f2; gain = 1.0f;    row = row4 - NN; }
            u32 wb = ((const u32*)src)[(size_t)row * 64 + lane];
            unsigned e = (wb >> 7) & 0xFF;
            int isF32 = (__popcll(__ballot(e >= 100 && e <= 140)) < 32);
            float x0, x1;
            if (isF32) {
                float2 v = ((const float2*)src)[(size_t)row * 64 + lane];
                x0 = v.x; x1 = v.y;
            } else {
                x0 = bf2f((u16)(wb & 0xFFFF));
                x1 = bf2f((u16)(wb >> 16));
            }
            float ss = wsum(x0 * x0 + x1 * x1);
            float sc = gain / fmaxf(sqrtf(ss), 1e-12f);
            u32 outw = (u32)f2bf(x0 * sc) | ((u32)f2bf(x1 * sc) << 16);
            ((u32*)dst)[(size_t)row * 64 + lane] = outw;
        }
    } else {
        int db = b - 1024;                    // 0..7
        if (db == 0 && tid < 4) sums[tid] = 0.0f;   // Lsum, Jsum, done, spare
        #pragma unroll
        for (int r = 0; r < 4; r++) {
            int idx = db * 1024 + r * 256 + tid;   // target index 0..8191
            // int64-vs-int32 detect on odd dwords, in-bounds under both widths
            int k = (idx >> 1) & 4095;
            int odd = traw[2 * k + 1];
            int is32 = (__ballot(odd != 0) != 0ull);
            int t = (is32 ? traw[idx] : traw[2 * idx]) & 127;
            tgt32[idx] = t;
        }
    }
}

// ---- fused NCE (blocks < 1024) + JSD (blocks >= 1024) --------------------
// NCE: 128 i-rows x 512 j-strip. B double-buffered in padded LDS, ONE
// barrier per tile. Per row accumulate P = sum_j 2^s2, Q = sum_pos 2^s2,
// S = sum_pos s2; PLAIN stores to private strip-partial slots (atomics to
// global are memory-side RMWs on CDNA4 -- 10x cost, r8 lesson). No fences.
__global__ __launch_bounds__(256, 4) void main_kernel(const u16* __restrict__ f1,
                                                      const u16* __restrict__ f2,
                                                      const int* __restrict__ tgt,
                                                      const void* __restrict__ ls,
                                                      const void* __restrict__ lt,
                                                      float* __restrict__ Pp,
                                                      float* __restrict__ Qp,
                                                      float* __restrict__ Sp,
                                                      float* __restrict__ sums) {
    __shared__ u16 lds[2][64 * LROW];   // 33792 B
    __shared__ float sred[4];
    int bx = blockIdx.x;
    int tid = threadIdx.x;
    int w = tid >> 6, lane = tid & 63;

    if (bx < GRID_NCE) {
        // ------------------- NCE path -------------------
        int strip = bx & (NSTRIP - 1);
        int ib = bx >> 4;
        int quad = lane >> 4, lcol = lane & 15;
        int ibase = ib * 128 + w * 32;

        v8s a0[4], a1[4];
        #pragma unroll
        for (int t = 0; t < 4; t++) {
            int k = t * 32 + quad * 8;
            a0[t] = *(const v8s*)(f1 + (size_t)(ibase + lcol) * DD + k);
            a1[t] = *(const v8s*)(f1 + (size_t)(ibase + 16 + lcol) * DD + k);
        }
        int ti[8];
        #pragma unroll
        for (int a = 0; a < 2; a++)
            #pragma unroll
            for (int v = 0; v < 4; v++)
                ti[a * 4 + v] = tgt[ibase + a * 16 + quad * 4 + v];

        float P[8] = {}, Q[8] = {}, S[8] = {};

        int srow = tid >> 4;           // 0..15
        int schunk = tid & 15;         // 0..15
        const u16* gb = f2 + (size_t)strip * JPER * DD;

        float4 st[4];
        #pragma unroll
        for (int r = 0; r < 4; r++)
            st[r] = *(const float4*)(gb + (size_t)(r * 16 + srow) * DD + schunk * 8);

        for (int it = 0; it < NTILE; ++it) {
            u16* buf = lds[it & 1];
            #pragma unroll
            for (int r = 0; r < 4; r++)
                *(float4*)(buf + (r * 16 + srow) * LROW + schunk * 8) = st[r];
            __syncthreads();
            if (it + 1 < NTILE) {     // prefetch next tile; hidden by compute
                const u16* g2 = gb + (size_t)(it + 1) * 64 * DD;
                #pragma unroll
                for (int r = 0; r < 4; r++)
                    st[r] = *(const float4*)(g2 + (size_t)(r * 16 + srow) * DD + schunk * 8);
            }
            int jb = strip * JPER + it * 64;
            int tj0 = tgt[jb + lcol];
            int tj1 = tgt[jb + 16 + lcol];
            int tj2 = tgt[jb + 32 + lcol];
            int tj3 = tgt[jb + 48 + lcol];

            const u16* lb = buf + lcol * LROW + quad * 8;
            v4f zero = {0.f, 0.f, 0.f, 0.f};
            v4f acc[8] = {zero, zero, zero, zero, zero, zero, zero, zero};
            #pragma unroll
            for (int t = 0; t < 4; t++) {
                v8s b0 = *(const v8s*)(lb + 0 * 16 * LROW + t * 32);
                v8s b1 = *(const v8s*)(lb + 1 * 16 * LROW + t * 32);
                v8s b2 = *(const v8s*)(lb + 2 * 16 * LROW + t * 32);
                v8s b3 = *(const v8s*)(lb + 3 * 16 * LROW + t * 32);
                acc[0] = __builtin_amdgcn_mfma_f32_16x16x32_bf16(a0[t], b0, acc[0], 0, 0, 0);
                acc[1] = __builtin_amdgcn_mfma_f32_16x16x32_bf16(a0[t], b1, acc[1], 0, 0, 0);
                acc[2] = __builtin_amdgcn_mfma_f32_16x16x32_bf16(a0[t], b2, acc[2], 0, 0, 0);
                acc[3] = __builtin_amdgcn_mfma_f32_16x16x32_bf16(a0[t], b3, acc[3], 0, 0, 0);
                acc[4] = __builtin_amdgcn_mfma_f32_16x16x32_bf16(a1[t], b0, acc[4], 0, 0, 0);
                acc[5] = __builtin_amdgcn_mfma_f32_16x16x32_bf16(a1[t], b1, acc[5], 0, 0, 0);
                acc[6] = __builtin_amdgcn_mfma_f32_16x16x32_bf16(a1[t], b2, acc[6], 0, 0, 0);
                acc[7] = __builtin_amdgcn_mfma_f32_16x16x32_bf16(a1[t], b3, acc[7], 0, 0, 0);
            }
            #pragma unroll
            for (int a = 0; a < 2; a++) {
                #pragma unroll
                for (int v = 0; v < 4; v++) {
                    int t_i = ti[a * 4 + v];
                    #pragma unroll
                    for (int jf = 0; jf < 4; jf++) {
                        float s2 = acc[a * 4 + jf][v];
                        float e1 = EXP2(s2);
                        int tj = (jf == 0) ? tj0 : (jf == 1) ? tj1 : (jf == 2) ? tj2 : tj3;
                        bool pos = (tj == t_i);
                        P[a * 4 + v] += e1;
                        Q[a * 4 + v] += pos ? e1 : 0.0f;
                        S[a * 4 + v] += pos ? s2 : 0.0f;
                    }
                }
            }
        }

        #pragma unroll
        for (int a = 0; a < 2; a++) {
            #pragma unroll
            for (int v = 0; v < 4; v++) {
                float p = P[a * 4 + v], q = Q[a * 4 + v], s = S[a * 4 + v];
                #pragma unroll
                for (int m = 1; m < 16; m <<= 1) {
                    p += __shfl_xor(p, m, 64);
                    q += __shfl_xor(q, m, 64);
                    s += __shfl_xor(s, m, 64);
                }
                if (lcol == 0) {
                    size_t idx = (size_t)strip * NN + ibase + a * 16 + quad * 4 + v;
                    Pp[idx] = p;   // plain stores -- NOT atomics (r8 lesson)
                    Qp[idx] = q;
                    Sp[idx] = s;
                }
            }
        }
    } else {
        // ------------------- JSD path (wave per row) -------------------
        int row = (bx - GRID_NCE) * 4 + w;
        u32 wb = ((const u32*)ls)[(size_t)row * 500 + lane];
        unsigned e = (wb >> 7) & 0xFF;
        int isF32 = (__popcll(__ballot(e >= 100 && e <= 140)) < 32);

        float xs[16], xt[16];
        #pragma unroll
        for (int c = 0; c < 4; c++) {
            int idx = c * 256 + lane * 4;
            if (idx < CC) {
                if (isF32) {
                    float4 a = *(const float4*)((const float*)ls + (size_t)row * CC + idx);
                    float4 b = *(const float4*)((const float*)lt + (size_t)row * CC + idx);
                    xs[c*4+0] = a.x; xs[c*4+1] = a.y; xs[c*4+2] = a.z; xs[c*4+3] = a.w;
                    xt[c*4+0] = b.x; xt[c*4+1] = b.y; xt[c*4+2] = b.z; xt[c*4+3] = b.w;
                } else {
                    ushort4 a = *(const ushort4*)((const u16*)ls + (size_t)row * CC + idx);
                    ushort4 b = *(const ushort4*)((const u16*)lt + (size_t)row * CC + idx);
                    xs[c*4+0] = bf2f(a.x); xs[c*4+1] = bf2f(a.y); xs[c*4+2] = bf2f(a.z); xs[c*4+3] = bf2f(a.w);
                    xt[c*4+0] = bf2f(b.x); xt[c*4+1] = bf2f(b.y); xt[c*4+2] = bf2f(b.z); xt[c*4+3] = bf2f(b.w);
                }
            } else {
                #pragma unroll
                for (int q = 0; q < 4; q++) { xs[c*4+q] = -1e30f; xt[c*4+q] = -1e30f; }
            }
        }
        float ms = -1e30f, mt = -1e30f;
        #pragma unroll
        for (int q = 0; q < 16; q++) { ms = fmaxf(ms, xs[q]); mt = fmaxf(mt, xt[q]); }
        ms = wmax(ms); mt = wmax(mt);
        float es = 0.f, et = 0.f;
        #pragma unroll
        for (int q = 0; q < 16; q++) { es += __expf(xs[q] - ms); et += __expf(xt[q] - mt); }
        es = wsum(es); et = wsum(et);
        float lse_s = ms + __logf(es), lse_t = mt + __logf(et);
        float contrib = 0.f;
        #pragma unroll
        for (int q = 0; q < 16; q++) {
            float lps = xs[q] - lse_s, lpt = xt[q] - lse_t;
            contrib += (lpt - lps) * (__expf(lpt) - __expf(lps));
        }
        contrib = wsum(contrib);
        if (lane == 0) sred[w] = contrib;
        __syncthreads();
        if (tid == 0) atomicAdd(&sums[1], sred[0] + sred[1] + sred[2] + sred[3]);
    }
}

// ---- rowred + finalize ---------------------------------------------------
// 32 blocks x 256, one row per thread. LDS histogram for class counts;
// strip-partial reduction with plain loads (kernel-boundary visibility).
__global__ __launch_bounds__(256) void rowred_kernel(const float* __restrict__ Pp,
                                                     const float* __restrict__ Qp,
                                                     const float* __restrict__ Sp,
                                                     const int* __restrict__ tgt,
                                                     float* __restrict__ sums,
                                                     u32* __restrict__ out) {
    __shared__ int h[128];
    __shared__ float sb[4];
    __shared__ int lastf;
    int tid = threadIdx.x;
    if (tid < 128) h[tid] = 0;
    __syncthreads();
    for (int i = tid; i < NN; i += 256) atomicAdd(&h[tgt[i]], 1);
    __syncthreads();

    int i = blockIdx.x * 256 + tid;
    float P = 0.f, Q = 0.f, S = 0.f;
    #pragma unroll
    for (int s = 0; s < NSTRIP; s++) {
        P += Pp[(size_t)s * NN + i];
        Q += Qp[(size_t)s * NN + i];
        S += Sp[(size_t)s * NN + i];
    }
    int cnt = h[tgt[i]];
    float pos = LN2 * LOG2(P) - LN2 * S / (float)cnt;
    float neg = (1.0f - Q / P) / (float)(NN - cnt);
    float l = wsum(pos + neg);
    if ((tid & 63) == 0) sb[tid >> 6] = l;
    __syncthreads();
    if (tid == 0) {
        atomicAdd(&sums[0], sb[0] + sb[1] + sb[2] + sb[3]);
        __threadfence();
        int* done = (int*)sums + 2;
        lastf = (atomicAdd(done, 1) == 31);
    }
    __syncthreads();
    if (!lastf) return;
    if (tid == 0) {
        float Lsum = __hip_atomic_load(&sums[0], __ATOMIC_RELAXED, __HIP_MEMORY_SCOPE_AGENT);
        float Jsum = __hip_atomic_load(&sums[1], __ATOMIC_RELAXED, __HIP_MEMORY_SCOPE_AGENT);
        float loss = (Lsum + 0.5f * Jsum) / (float)NN;
        u32 fb = __float_as_uint(loss);
        out[0] = (fb & 0xFFFF0000u) | (u32)f2bf(loss);   // dual bf16/fp32 word
    }
}

// ---- launch --------------------------------------------------------------
extern "C" void kernel_launch(void* const* d_in, const int* in_sizes, int n_in,
                              void* d_out, int out_size, void* d_ws, size_t ws_size,
                              hipStream_t stream) {
    const void* fs = d_in[0];
    const void* ft = d_in[1];
    const void* ls = d_in[2];
    const void* lt = d_in[3];
    const int* tgt_raw = (const int*)d_in[4];

    char* wsp = (char*)d_ws;
    u16*   f1    = (u16*)(wsp + 0);           // 2 MiB
    u16*   f2    = (u16*)(wsp + 2097152);     // 2 MiB
    float* Pp    = (float*)(wsp + 4194304);   // 512 KiB (16 x 8192)
    float* Qp    = (float*)(wsp + 4718592);   // 512 KiB
    float* Sp    = (float*)(wsp + 5242880);   // 512 KiB
    float* sums  = (float*)(wsp + 5767168);   // 16 B (Lsum, Jsum, done, spare)
    int*   tgt32 = (int*)(wsp + 5767424);     // 32 KiB

    prep_kernel<<<1024 + 8, 256, 0, stream>>>(fs, ft, tgt_raw, f1, f2, tgt32, sums);
    main_kernel<<<GRID_TOT, 256, 0, stream>>>(f1, f2, tgt32, ls, lt, Pp, Qp, Sp, sums);
    rowred_kernel<<<32, 256, 0, stream>>>(Pp, Qp, Sp, tgt32, sums, (u32*)d_out);
}

// Round 10
// 162.784 us; speedup vs baseline: 3.1359x; 1.3660x over previous
//
#include <hip/hip_runtime.h>
#include <hip/hip_bf16.h>

// Problem constants
#define NN 8192
#define DD 128
#define CC 1000
#define LN2 0.69314718f
#define G_SCALE 14.42695041f   // 10/ln2 : MFMA emits log2-domain scores
#define NSTRIP 16
#define JPER   512             // 8192/16 j-columns per strip
#define NTILE  8               // JPER/64
#define LROW   128             // u16 per LDS B-row; no pad (global_load_lds is
                               // contiguous); bank conflicts killed by XOR swizzle
#define GRID_NCE 1024          // NSTRIP * 64
#define GRID_TOT 3072          // + NN/4 JSD blocks

typedef short v8s __attribute__((ext_vector_type(8)));
typedef float v4f __attribute__((ext_vector_type(4)));
typedef unsigned short u16;
typedef unsigned int u32;

typedef __attribute__((address_space(1))) const unsigned char ga_t;
typedef __attribute__((address_space(3))) unsigned char la_t;
#define GLOAD_LDS16(g, l) __builtin_amdgcn_global_load_lds((ga_t*)(g), (la_t*)(l), 16, 0, 0)

#if __has_builtin(__builtin_amdgcn_exp2f)
#define EXP2(x) __builtin_amdgcn_exp2f(x)
#else
#define EXP2(x) exp2f(x)
#endif
#if __has_builtin(__builtin_amdgcn_logf)
#define LOG2(x) __builtin_amdgcn_logf(x)
#else
#define LOG2(x) log2f(x)
#endif

// ---- helpers -------------------------------------------------------------
static __device__ __forceinline__ float bf2f(u16 u) {
    union { float f; u32 i; } x; x.i = ((u32)u) << 16; return x.f;
}
static __device__ __forceinline__ u16 f2bf(float f) {
    u32 x = __float_as_uint(f);
    return (u16)((x + 0x7FFFu + ((x >> 16) & 1u)) >> 16);  // RNE
}
static __device__ __forceinline__ float wsum(float v) {
    #pragma unroll
    for (int m = 1; m < 64; m <<= 1) v += __shfl_xor(v, m, 64);
    return v;
}
static __device__ __forceinline__ float wmax(float v) {
    #pragma unroll
    for (int m = 1; m < 64; m <<= 1) v = fmaxf(v, __shfl_xor(v, m, 64));
    return v;
}

// ---- prep: barrier-free, one WAVE per feature row (4 rows per wave) ------
__global__ __launch_bounds__(256) void prep_kernel(const void* __restrict__ fs,
                                                   const void* __restrict__ ft,
                                                   const int* __restrict__ traw,
                                                   u16* __restrict__ f1, u16* __restrict__ f2,
                                                   int* __restrict__ tgt32,
                                                   float* __restrict__ sums) {
    int b = blockIdx.x, tid = threadIdx.x;
    int w = tid >> 6, lane = tid & 63;
    if (b < 1024) {
        #pragma unroll
        for (int r = 0; r < 4; r++) {
            int row4 = b * 16 + w * 4 + r;        // 0..16383
            const void* src; u16* dst; float gain; int row;
            if (row4 < NN) { src = fs; dst = f1; gain = G_SCALE; row = row4; }
            else           { src = ft; dst = f2; gain = 1.0f;    row = row4 - NN; }
            u32 wb = ((const u32*)src)[(size_t)row * 64 + lane];
            unsigned e = (wb >> 7) & 0xFF;
            int isF32 = (__popcll(__ballot(e >= 100 && e <= 140)) < 32);
            float x0, x1;
            if (isF32) {
                float2 v = ((const float2*)src)[(size_t)row * 64 + lane];
                x0 = v.x; x1 = v.y;
            } else {
                x0 = bf2f((u16)(wb & 0xFFFF));
                x1 = bf2f((u16)(wb >> 16));
            }
            float ss = wsum(x0 * x0 + x1 * x1);
            float sc = gain / fmaxf(sqrtf(ss), 1e-12f);
            u32 outw = (u32)f2bf(x0 * sc) | ((u32)f2bf(x1 * sc) << 16);
            ((u32*)dst)[(size_t)row * 64 + lane] = outw;
        }
    } else {
        int db = b - 1024;                    // 0..7
        if (db == 0 && tid < 4) sums[tid] = 0.0f;   // Lsum, Jsum, done, spare
        #pragma unroll
        for (int r = 0; r < 4; r++) {
            int idx = db * 1024 + r * 256 + tid;   // target index 0..8191
            int k = (idx >> 1) & 4095;             // odd-dword probe, in-bounds both ways
            int odd = traw[2 * k + 1];
            int is32 = (__ballot(odd != 0) != 0ull);
            int t = (is32 ? traw[idx] : traw[2 * idx]) & 127;
            tgt32[idx] = t;
        }
    }
}

// ---- fused NCE (blocks < 1024) + JSD (blocks >= 1024) --------------------
// NCE: 128 i-rows x 512 j-strip. B staged by global_load_lds (async DMA,
// no VGPR round-trip) into an XOR-swizzled layout: LDS slot (row, s) holds
// global chunk s ^ (row & 15). b-frag reads then hit each LDS bank-group
// exactly twice -> conflict-free without padding. Double buffer, one
// barrier per tile; prefetch issued right after the barrier. Plain stores
// to strip-partial slots (no atomics/fences on the hot path: r7/r8 lessons).
__global__ __launch_bounds__(256) void main_kernel(const u16* __restrict__ f1,
                                                   const u16* __restrict__ f2,
                                                   const int* __restrict__ tgt,
                                                   const void* __restrict__ ls,
                                                   const void* __restrict__ lt,
                                                   float* __restrict__ Pp,
                                                   float* __restrict__ Qp,
                                                   float* __restrict__ Sp,
                                                   float* __restrict__ sums) {
    __shared__ u16 lds[2][64 * LROW];   // 2 x 16 KiB
    __shared__ float sred[4];
    int bx = blockIdx.x;
    int tid = threadIdx.x;
    int w = tid >> 6, lane = tid & 63;

    if (bx < GRID_NCE) {
        // ------------------- NCE path -------------------
        int strip = bx & (NSTRIP - 1);
        int ib = bx >> 4;
        int quad = lane >> 4, lcol = lane & 15;
        int ibase = ib * 128 + w * 32;

        v8s a0[4], a1[4];
        #pragma unroll
        for (int t = 0; t < 4; t++) {
            int k = t * 32 + quad * 8;
            a0[t] = *(const v8s*)(f1 + (size_t)(ibase + lcol) * DD + k);
            a1[t] = *(const v8s*)(f1 + (size_t)(ibase + 16 + lcol) * DD + k);
        }
        int ti[8];
        #pragma unroll
        for (int a = 0; a < 2; a++)
            #pragma unroll
            for (int v = 0; v < 4; v++)
                ti[a * 4 + v] = tgt[ibase + a * 16 + quad * 4 + v];

        float P[8] = {}, Q[8] = {}, S[8] = {};

        // staging geometry: wave w, round r covers rows r*16 + 4w + (lane>>4)
        int rrl = 4 * w + (lane >> 4);          // row key within 16 (0..15)
        int cg = (lane & 15) ^ rrl;             // swizzled source chunk
        const u16* gb = f2 + (size_t)strip * JPER * DD + (size_t)rrl * DD + cg * 8;
        // per-wave-uniform LDS byte base for round r: (r*16 + 4w) * 256
        int ldsbase = 4 * w * 256;

        // preload tile 0
        #pragma unroll
        for (int r = 0; r < 4; r++)
            GLOAD_LDS16(gb + (size_t)r * 16 * DD,
                        (unsigned char*)lds[0] + ldsbase + r * 16 * 256);

        for (int it = 0; it < NTILE; ++it) {
            __syncthreads();   // vmcnt drain: tile `it` resident; prev reads done
            if (it + 1 < NTILE) {
                const u16* g2 = gb + (size_t)(it + 1) * 64 * DD;
                unsigned char* l2 = (unsigned char*)lds[(it + 1) & 1] + ldsbase;
                #pragma unroll
                for (int r = 0; r < 4; r++)
                    GLOAD_LDS16(g2 + (size_t)r * 16 * DD, l2 + r * 16 * 256);
            }
            int jb = strip * JPER + it * 64;
            int tj0 = tgt[jb + lcol];
            int tj1 = tgt[jb + 16 + lcol];
            int tj2 = tgt[jb + 32 + lcol];
            int tj3 = tgt[jb + 48 + lcol];

            const u16* buf = lds[it & 1];
            v4f zero = {0.f, 0.f, 0.f, 0.f};
            v4f acc[8] = {zero, zero, zero, zero, zero, zero, zero, zero};
            #pragma unroll
            for (int t = 0; t < 4; t++) {
                int s = ((quad + 4 * t) ^ lcol) * 8;      // swizzled chunk offset (u16)
                v8s b0 = *(const v8s*)(buf + (lcol)*LROW + s);
                v8s b1 = *(const v8s*)(buf + (16 + lcol) * LROW + s);
                v8s b2 = *(const v8s*)(buf + (32 + lcol) * LROW + s);
                v8s b3 = *(const v8s*)(buf + (48 + lcol) * LROW + s);
                acc[0] = __builtin_amdgcn_mfma_f32_16x16x32_bf16(a0[t], b0, acc[0], 0, 0, 0);
                acc[1] = __builtin_amdgcn_mfma_f32_16x16x32_bf16(a0[t], b1, acc[1], 0, 0, 0);
                acc[2] = __builtin_amdgcn_mfma_f32_16x16x32_bf16(a0[t], b2, acc[2], 0, 0, 0);
                acc[3] = __builtin_amdgcn_mfma_f32_16x16x32_bf16(a0[t], b3, acc[3], 0, 0, 0);
                acc[4] = __builtin_amdgcn_mfma_f32_16x16x32_bf16(a1[t], b0, acc[4], 0, 0, 0);
                acc[5] = __builtin_amdgcn_mfma_f32_16x16x32_bf16(a1[t], b1, acc[5], 0, 0, 0);
                acc[6] = __builtin_amdgcn_mfma_f32_16x16x32_bf16(a1[t], b2, acc[6], 0, 0, 0);
                acc[7] = __builtin_amdgcn_mfma_f32_16x16x32_bf16(a1[t], b3, acc[7], 0, 0, 0);
            }
            #pragma unroll
            for (int a = 0; a < 2; a++) {
                #pragma unroll
                for (int v = 0; v < 4; v++) {
                    int t_i = ti[a * 4 + v];
                    #pragma unroll
                    for (int jf = 0; jf < 4; jf++) {
                        float s2 = acc[a * 4 + jf][v];
                        float e1 = EXP2(s2);
                        int tj = (jf == 0) ? tj0 : (jf == 1) ? tj1 : (jf == 2) ? tj2 : tj3;
                        bool pos = (tj == t_i);
                        P[a * 4 + v] += e1;
                        Q[a * 4 + v] += pos ? e1 : 0.0f;
                        S[a * 4 + v] += pos ? s2 : 0.0f;
                    }
                }
            }
        }

        #pragma unroll
        for (int a = 0; a < 2; a++) {
            #pragma unroll
            for (int v = 0; v < 4; v++) {
                float p = P[a * 4 + v], q = Q[a * 4 + v], s = S[a * 4 + v];
                #pragma unroll
                for (int m = 1; m < 16; m <<= 1) {
                    p += __shfl_xor(p, m, 64);
                    q += __shfl_xor(q, m, 64);
                    s += __shfl_xor(s, m, 64);
                }
                if (lcol == 0) {
                    size_t idx = (size_t)strip * NN + ibase + a * 16 + quad * 4 + v;
                    Pp[idx] = p;   // plain stores -- NOT atomics (r8 lesson)
                    Qp[idx] = q;
                    Sp[idx] = s;
                }
            }
        }
    } else {
        // ------------------- JSD path (wave per row) -------------------
        int row = (bx - GRID_NCE) * 4 + w;
        u32 wb = ((const u32*)ls)[(size_t)row * 500 + lane];
        unsigned e = (wb >> 7) & 0xFF;
        int isF32 = (__popcll(__ballot(e >= 100 && e <= 140)) < 32);

        float xs[16], xt[16];
        #pragma unroll
        for (int c = 0; c < 4; c++) {
            int idx = c * 256 + lane * 4;
            if (idx < CC) {
                if (isF32) {
                    float4 a = *(const float4*)((const float*)ls + (size_t)row * CC + idx);
                    float4 b = *(const float4*)((const float*)lt + (size_t)row * CC + idx);
                    xs[c*4+0] = a.x; xs[c*4+1] = a.y; xs[c*4+2] = a.z; xs[c*4+3] = a.w;
                    xt[c*4+0] = b.x; xt[c*4+1] = b.y; xt[c*4+2] = b.z; xt[c*4+3] = b.w;
                } else {
                    ushort4 a = *(const ushort4*)((const u16*)ls + (size_t)row * CC + idx);
                    ushort4 b = *(const ushort4*)((const u16*)lt + (size_t)row * CC + idx);
                    xs[c*4+0] = bf2f(a.x); xs[c*4+1] = bf2f(a.y); xs[c*4+2] = bf2f(a.z); xs[c*4+3] = bf2f(a.w);
                    xt[c*4+0] = bf2f(b.x); xt[c*4+1] = bf2f(b.y); xt[c*4+2] = bf2f(b.z); xt[c*4+3] = bf2f(b.w);
                }
            } else {
                #pragma unroll
                for (int q = 0; q < 4; q++) { xs[c*4+q] = -1e30f; xt[c*4+q] = -1e30f; }
            }
        }
        float ms = -1e30f, mt = -1e30f;
        #pragma unroll
        for (int q = 0; q < 16; q++) { ms = fmaxf(ms, xs[q]); mt = fmaxf(mt, xt[q]); }
        ms = wmax(ms); mt = wmax(mt);
        float es = 0.f, et = 0.f;
        #pragma unroll
        for (int q = 0; q < 16; q++) { es += __expf(xs[q] - ms); et += __expf(xt[q] - mt); }
        es = wsum(es); et = wsum(et);
        float lse_s = ms + __logf(es), lse_t = mt + __logf(et);
        float contrib = 0.f;
        #pragma unroll
        for (int q = 0; q < 16; q++) {
            float lps = xs[q] - lse_s, lpt = xt[q] - lse_t;
            contrib += (lpt - lps) * (__expf(lpt) - __expf(lps));
        }
        contrib = wsum(contrib);
        if (lane == 0) sred[w] = contrib;
        __syncthreads();
        if (tid == 0) atomicAdd(&sums[1], sred[0] + sred[1] + sred[2] + sred[3]);
    }
}

// ---- rowred + finalize ---------------------------------------------------
__global__ __launch_bounds__(256) void rowred_kernel(const float* __restrict__ Pp,
                                                     const float* __restrict__ Qp,
                                                     const float* __restrict__ Sp,
                                                     const int* __restrict__ tgt,
                                                     float* __restrict__ sums,
                                                     u32* __restrict__ out) {
    __shared__ int h[128];
    __shared__ float sb[4];
    __shared__ int lastf;
    int tid = threadIdx.x;
    if (tid < 128) h[tid] = 0;
    __syncthreads();
    for (int i = tid; i < NN; i += 256) atomicAdd(&h[tgt[i]], 1);
    __syncthreads();

    int i = blockIdx.x * 256 + tid;
    float P = 0.f, Q = 0.f, S = 0.f;
    #pragma unroll
    for (int s = 0; s < NSTRIP; s++) {
        P += Pp[(size_t)s * NN + i];
        Q += Qp[(size_t)s * NN + i];
        S += Sp[(size_t)s * NN + i];
    }
    int cnt = h[tgt[i]];
    float pos = LN2 * LOG2(P) - LN2 * S / (float)cnt;
    float neg = (1.0f - Q / P) / (float)(NN - cnt);
    float l = wsum(pos + neg);
    if ((tid & 63) == 0) sb[tid >> 6] = l;
    __syncthreads();
    if (tid == 0) {
        atomicAdd(&sums[0], sb[0] + sb[1] + sb[2] + sb[3]);
        __threadfence();
        int* done = (int*)sums + 2;
        lastf = (atomicAdd(done, 1) == 31);
    }
    __syncthreads();
    if (!lastf) return;
    if (tid == 0) {
        float Lsum = __hip_atomic_load(&sums[0], __ATOMIC_RELAXED, __HIP_MEMORY_SCOPE_AGENT);
        float Jsum = __hip_atomic_load(&sums[1], __ATOMIC_RELAXED, __HIP_MEMORY_SCOPE_AGENT);
        float loss = (Lsum + 0.5f * Jsum) / (float)NN;
        u32 fb = __float_as_uint(loss);
        out[0] = (fb & 0xFFFF0000u) | (u32)f2bf(loss);   // dual bf16/fp32 word
    }
}

// ---- launch --------------------------------------------------------------
extern "C" void kernel_launch(void* const* d_in, const int* in_sizes, int n_in,
                              void* d_out, int out_size, void* d_ws, size_t ws_size,
                              hipStream_t stream) {
    const void* fs = d_in[0];
    const void* ft = d_in[1];
    const void* ls = d_in[2];
    const void* lt = d_in[3];
    const int* tgt_raw = (const int*)d_in[4];

    char* wsp = (char*)d_ws;
    u16*   f1    = (u16*)(wsp + 0);           // 2 MiB
    u16*   f2    = (u16*)(wsp + 2097152);     // 2 MiB
    float* Pp    = (float*)(wsp + 4194304);   // 512 KiB (16 x 8192)
    float* Qp    = (float*)(wsp + 4718592);   // 512 KiB
    float* Sp    = (float*)(wsp + 5242880);   // 512 KiB
    float* sums  = (float*)(wsp + 5767168);   // 16 B (Lsum, Jsum, done, spare)
    int*   tgt32 = (int*)(wsp + 5767424);     // 32 KiB

    prep_kernel<<<1024 + 8, 256, 0, stream>>>(fs, ft, tgt_raw, f1, f2, tgt32, sums);
    main_kernel<<<GRID_TOT, 256, 0, stream>>>(f1, f2, tgt32, ls, lt, Pp, Qp, Sp, sums);
    rowred_kernel<<<32, 256, 0, stream>>>(Pp, Qp, Sp, tgt32, sums, (u32*)d_out);
}